// Round 14
// baseline (519.257 us; speedup 1.0000x reference)
//
#include <hip/hip_runtime.h>
#include <math.h>
#include <stdint.h>

// Problem dims (fixed by reference)
#define BB   64
#define SS   60
#define ENCD 1024
#define ED   512
#define HD   512
#define VD   32000
#define TT   20

typedef unsigned short u16;
typedef __attribute__((ext_vector_type(8))) short short8v;   // 8 bf16 = 4 VGPR
typedef __attribute__((ext_vector_type(4))) float f32x4;

__device__ __forceinline__ u16 f2bf(float x) {   // RNE float->bf16
  unsigned int u = __float_as_uint(x);
  return (u16)((u + 0x7FFFu + ((u >> 16) & 1u)) >> 16);
}
__device__ __forceinline__ float bf2f(u16 b) {
  return __uint_as_float((unsigned)b << 16);
}

// ---------------------------------------------------------------------------
__global__ __launch_bounds__(256) void init_kernel(float* __restrict__ out,
                                                   float* __restrict__ h,
                                                   float* __restrict__ c) {
  int i = blockIdx.x * 256 + threadIdx.x;
  if (i < BB * VD) {
    int b = i / VD, v = i - b * VD;
    out[(long)b * (TT * VD) + v] = 0.f;
  }
  if (i < BB * HD) { h[i] = 0.f; c[i] = 0.f; }
}

// ---------------------------------------------------------------------------
__global__ __launch_bounds__(256) void convert_bf16_k(const float* __restrict__ src,
                                                      u16* __restrict__ dst, long n) {
  long i = ((long)blockIdx.x * 256 + threadIdx.x) * 8;
  if (i + 8 <= n) {
    float4 a = *reinterpret_cast<const float4*>(src + i);
    float4 b = *reinterpret_cast<const float4*>(src + i + 4);
    uint4 o;
    o.x = (unsigned)f2bf(a.x) | ((unsigned)f2bf(a.y) << 16);
    o.y = (unsigned)f2bf(a.z) | ((unsigned)f2bf(a.w) << 16);
    o.z = (unsigned)f2bf(b.x) | ((unsigned)f2bf(b.y) << 16);
    o.w = (unsigned)f2bf(b.z) | ((unsigned)f2bf(b.w) << 16);
    *reinterpret_cast<uint4*>(dst + i) = o;
  }
}

// ---------------------------------------------------------------------------
__global__ __launch_bounds__(256) void split_pair_k(const float* __restrict__ src,
                                                    u16* __restrict__ bf,
                                                    u16* __restrict__ er, long n) {
  long i = ((long)blockIdx.x * 256 + threadIdx.x) * 8;
  if (i + 8 <= n) {
    #pragma unroll
    for (int j = 0; j < 8; ++j) {
      float v = src[i + j];
      u16 b = f2bf(v);
      bf[i + j] = b;
      er[i + j] = f2bf(v - bf2f(b));
    }
  }
}

// ---------------------------------------------------------------------------
__global__ __launch_bounds__(256) void split_wg_k(
    const float* __restrict__ Wih, const float* __restrict__ Whh,
    u16* __restrict__ wb, u16* __restrict__ we) {
  int n = blockIdx.x;
  int k0 = threadIdx.x * 8;
  #pragma unroll
  for (int j = 0; j < 8; ++j) {
    int k = k0 + j;
    float v = (k < 1536) ? Wih[(long)n * 1536 + k] : Whh[(long)n * 512 + (k - 1536)];
    u16 b = f2bf(v);
    wb[(long)n * 2048 + k] = b;
    we[(long)n * 2048 + k] = f2bf(v - bf2f(b));
  }
}

// ---------------------------------------------------------------------------
__global__ __launch_bounds__(256) void gather_emb_split(
    const int* __restrict__ caps, const float* __restrict__ emb,
    u16* __restrict__ xb, u16* __restrict__ xe) {
  int r = blockIdx.x;                 // 0..1215
  int b = r & 63, t = r >> 6;
  int word = caps[b * TT + t];
  const float* src = emb + (long)word * ED;
  for (int k = threadIdx.x; k < ED; k += 256) {
    float v = src[k];
    u16 bb = f2bf(v);
    xb[(long)r * ED + k] = bb;
    xe[(long)r * ED + k] = f2bf(v - bf2f(bb));
  }
}

// ---------------------------------------------------------------------------
// Merged per-step kernel: z<6 -> gates split-bf16 MFMA (proven R8/R10);
// z>=6 -> fc slice for step t-1 (hbuf[t-1] ready: written by fused(t) which
// precedes this launch).  nt = (z-6)*32 + x, skip nt>=125; fc body identical
// arithmetic/order to the proven fc_tiled -> bit-identical output.
// 80 KB LDS: both block types fit 2/CU; fc slices run on CUs gates leaves idle.
// ---------------------------------------------------------------------------
__global__ __launch_bounds__(256) void gates_fc_mfma(
    const u16* __restrict__ xb, const u16* __restrict__ xe,
    const u16* __restrict__ wb, const u16* __restrict__ we,
    float* __restrict__ P,
    const u16* __restrict__ hb_fc,     // hbuf + (t-1)*B*H
    const u16* __restrict__ Wfc,       // [32000][512] bf16
    const float* __restrict__ fcb,
    float* __restrict__ out_fc,        // out + t*VD  (fc col s+1 = t)
    int fc_on) {
  __shared__ __align__(16) u16 lds[40960];   // 80 KB
  const int tid = threadIdx.x;
  const int w = tid >> 6, lane = tid & 63;
  const int frow = lane & 15, fgrp = lane >> 4;
  const int srow = tid >> 3, sslot = tid & 7;
  const int scol = (sslot ^ (srow & 7)) * 8;

  if (blockIdx.z < 6) {
    // ---------------- gates body ----------------
    const int n0 = blockIdx.x * 64;
    const int kz = blockIdx.z * 256;
    char* L = (char*)lds;

#define GT_STAGE(buf, kc) do {                                                     \
    _Pragma("unroll")                                                              \
    for (int ii = 0; ii < 2; ++ii) {                                               \
      int r_ = ii * 32 + srow;                                                     \
      __builtin_amdgcn_global_load_lds(                                            \
        (const __attribute__((address_space(1))) void*)(xb + (long)r_ * 2048 + (kc) + scol), \
        (__attribute__((address_space(3))) void*)(L + (buf) * 8192 + ii * 4096 + tid * 16), 16, 0, 0); \
      __builtin_amdgcn_global_load_lds(                                            \
        (const __attribute__((address_space(1))) void*)(xe + (long)r_ * 2048 + (kc) + scol), \
        (__attribute__((address_space(3))) void*)(L + 16384 + (buf) * 8192 + ii * 4096 + tid * 16), 16, 0, 0); \
      __builtin_amdgcn_global_load_lds(                                            \
        (const __attribute__((address_space(1))) void*)(wb + (long)(n0 + r_) * 2048 + (kc) + scol), \
        (__attribute__((address_space(3))) void*)(L + 32768 + (buf) * 8192 + ii * 4096 + tid * 16), 16, 0, 0); \
      __builtin_amdgcn_global_load_lds(                                            \
        (const __attribute__((address_space(1))) void*)(we + (long)(n0 + r_) * 2048 + (kc) + scol), \
        (__attribute__((address_space(3))) void*)(L + 49152 + (buf) * 8192 + ii * 4096 + tid * 16), 16, 0, 0); \
    }                                                                              \
  } while (0)

    f32x4 acc[4] = {{0.f,0.f,0.f,0.f},{0.f,0.f,0.f,0.f},{0.f,0.f,0.f,0.f},{0.f,0.f,0.f,0.f}};

    GT_STAGE(0, kz);
    asm volatile("s_waitcnt vmcnt(0)");
    __syncthreads();

    for (int kc = 0; kc < 4; ++kc) {
      const int cur = kc & 1;
      if (kc < 3) GT_STAGE(cur ^ 1, kz + (kc + 1) * 64);
      const char* Ab = L + cur * 8192;
      const char* Ae = L + 16384 + cur * 8192;
      const char* Bb = L + 32768 + cur * 8192;
      const char* Be = L + 49152 + cur * 8192;
      #pragma unroll
      for (int ks = 0; ks < 2; ++ks) {
        const int slot = ((ks * 4 + fgrp) ^ (frow & 7)) * 16;
        const int brow = (w * 16 + frow) * 128 + slot;
        short8v bbf = *reinterpret_cast<const short8v*>(Bb + brow);
        short8v bef = *reinterpret_cast<const short8v*>(Be + brow);
        #pragma unroll
        for (int m = 0; m < 4; ++m) {
          const int arow = (m * 16 + frow) * 128 + slot;
          short8v abf = *reinterpret_cast<const short8v*>(Ab + arow);
          short8v aef = *reinterpret_cast<const short8v*>(Ae + arow);
          acc[m] = __builtin_amdgcn_mfma_f32_16x16x32_bf16(abf, bbf, acc[m], 0, 0, 0);
          acc[m] = __builtin_amdgcn_mfma_f32_16x16x32_bf16(aef, bbf, acc[m], 0, 0, 0);
          acc[m] = __builtin_amdgcn_mfma_f32_16x16x32_bf16(abf, bef, acc[m], 0, 0, 0);
        }
      }
      asm volatile("s_waitcnt vmcnt(0)");
      __syncthreads();
    }

    float* Pz = P + (long)blockIdx.z * (BB * 2048);
    const int col = n0 + w * 16 + frow;
    #pragma unroll
    for (int m = 0; m < 4; ++m)
      #pragma unroll
      for (int r = 0; r < 4; ++r)
        Pz[(long)(m * 16 + fgrp * 4 + r) * 2048 + col] = acc[m][r];
#undef GT_STAGE
  } else {
    // ---------------- fc slice body (step s = t-1) ----------------
    if (!fc_on) return;
    const int nt = (blockIdx.z - 6) * 32 + blockIdx.x;
    if (nt >= 125) return;
    const int n0 = nt * 256;
    const u16* Ab = hb_fc;
    const u16* Wbase = Wfc + (long)n0 * HD;
    char* ldsb = (char*)lds;

#define FC_STAGE(buf, kc) do {                                                    \
    _Pragma("unroll")                                                             \
    for (int ii = 0; ii < 2; ++ii) {                                              \
      __builtin_amdgcn_global_load_lds(                                           \
        (const __attribute__((address_space(1))) void*)(Ab + (ii * 32 + srow) * HD + (kc) + scol), \
        (__attribute__((address_space(3))) void*)(ldsb + (buf) * 8192 + ii * 4096 + tid * 16), \
        16, 0, 0);                                                                \
    }                                                                             \
    _Pragma("unroll")                                                             \
    for (int ii = 0; ii < 8; ++ii) {                                              \
      __builtin_amdgcn_global_load_lds(                                           \
        (const __attribute__((address_space(1))) void*)(Wbase + (long)(ii * 32 + srow) * HD + (kc) + scol), \
        (__attribute__((address_space(3))) void*)(ldsb + 16384 + (buf) * 32768 + ii * 4096 + tid * 16), \
        16, 0, 0);                                                                \
    }                                                                             \
  } while (0)

    f32x4 acc[4][4] = {};

    FC_STAGE(0, 0);
    asm volatile("s_waitcnt vmcnt(0)");
    __syncthreads();

    for (int kc = 0; kc < 8; ++kc) {
      const int cur = kc & 1;
      if (kc < 7) FC_STAGE(cur ^ 1, (kc + 1) * 64);
      const char* Abuf = ldsb + cur * 8192;
      const char* Wbuf = ldsb + 16384 + cur * 32768;
      #pragma unroll
      for (int ks = 0; ks < 2; ++ks) {
        const int slot = ((ks * 4 + fgrp) ^ (frow & 7)) * 16;
        short8v af[4], wf[4];
        #pragma unroll
        for (int m = 0; m < 4; ++m)
          af[m] = *reinterpret_cast<const short8v*>(Abuf + (m * 16 + frow) * 128 + slot);
        #pragma unroll
        for (int n = 0; n < 4; ++n)
          wf[n] = *reinterpret_cast<const short8v*>(Wbuf + (w * 64 + n * 16 + frow) * 128 + slot);
        #pragma unroll
        for (int m = 0; m < 4; ++m)
          #pragma unroll
          for (int n = 0; n < 4; ++n)
            acc[m][n] = __builtin_amdgcn_mfma_f32_16x16x32_bf16(af[m], wf[n], acc[m][n], 0, 0, 0);
      }
      asm volatile("s_waitcnt vmcnt(0)");
      __syncthreads();
    }

    // coalesced epilogue via LDS (stride 260), verified R11-R13
    float* Lt = (float*)lds;     // 64*260*4 = 66560 B <= 80 KB
    #pragma unroll
    for (int n = 0; n < 4; ++n)
      #pragma unroll
      for (int m = 0; m < 4; ++m)
        #pragma unroll
        for (int r = 0; r < 4; ++r)
          Lt[(m * 16 + fgrp * 4 + r) * 260 + w * 64 + n * 16 + frow] = acc[m][n][r];
    __syncthreads();
    float4 bv4 = *reinterpret_cast<const float4*>(fcb + n0 + lane * 4);
    #pragma unroll
    for (int i = 0; i < 16; ++i) {
      int row = w * 16 + i;      // batch index b
      float4 v = *reinterpret_cast<const float4*>(&Lt[row * 260 + lane * 4]);
      v.x += bv4.x; v.y += bv4.y; v.z += bv4.z; v.w += bv4.w;
      *reinterpret_cast<float4*>(out_fc + (long)row * ((long)TT * VD) + n0 + lane * 4) = v;
    }
#undef FC_STAGE
  }
}

// ---------------------------------------------------------------------------
// Pemb batched GEMM (split-bf16 MFMA, proven R10)
// ---------------------------------------------------------------------------
__global__ __launch_bounds__(256) void pemb_mfma(
    const u16* __restrict__ xb, const u16* __restrict__ xe,   // [1216][512]
    const u16* __restrict__ wb, const u16* __restrict__ we,   // [2048][2048] (cols 0..511)
    float* __restrict__ Pemb) {                               // [19][64][2048]
  __shared__ __align__(16) u16 lds[32768];
  const int tid = threadIdx.x;
  const int n0 = blockIdx.x * 64;
  const int t  = blockIdx.y;
  const u16* Ab_g = xb + (long)t * 64 * ED;
  const u16* Ae_g = xe + (long)t * 64 * ED;
  const int w = tid >> 6, lane = tid & 63;
  const int frow = lane & 15, fgrp = lane >> 4;
  const int srow = tid >> 3, sslot = tid & 7;
  const int scol = (sslot ^ (srow & 7)) * 8;
  char* L = (char*)lds;

#define PE_STAGE(buf, kc) do {                                                     \
    _Pragma("unroll")                                                              \
    for (int ii = 0; ii < 2; ++ii) {                                               \
      int r_ = ii * 32 + srow;                                                     \
      __builtin_amdgcn_global_load_lds(                                            \
        (const __attribute__((address_space(1))) void*)(Ab_g + (long)r_ * ED + (kc) + scol), \
        (__attribute__((address_space(3))) void*)(L + (buf) * 8192 + ii * 4096 + tid * 16), 16, 0, 0); \
      __builtin_amdgcn_global_load_lds(                                            \
        (const __attribute__((address_space(1))) void*)(Ae_g + (long)r_ * ED + (kc) + scol), \
        (__attribute__((address_space(3))) void*)(L + 16384 + (buf) * 8192 + ii * 4096 + tid * 16), 16, 0, 0); \
      __builtin_amdgcn_global_load_lds(                                            \
        (const __attribute__((address_space(1))) void*)(wb + (long)(n0 + r_) * 2048 + (kc) + scol), \
        (__attribute__((address_space(3))) void*)(L + 32768 + (buf) * 8192 + ii * 4096 + tid * 16), 16, 0, 0); \
      __builtin_amdgcn_global_load_lds(                                            \
        (const __attribute__((address_space(1))) void*)(we + (long)(n0 + r_) * 2048 + (kc) + scol), \
        (__attribute__((address_space(3))) void*)(L + 49152 + (buf) * 8192 + ii * 4096 + tid * 16), 16, 0, 0); \
    }                                                                              \
  } while (0)

  f32x4 acc[4] = {{0.f,0.f,0.f,0.f},{0.f,0.f,0.f,0.f},{0.f,0.f,0.f,0.f},{0.f,0.f,0.f,0.f}};

  PE_STAGE(0, 0);
  asm volatile("s_waitcnt vmcnt(0)");
  __syncthreads();

  for (int kc = 0; kc < 8; ++kc) {
    const int cur = kc & 1;
    if (kc < 7) PE_STAGE(cur ^ 1, (kc + 1) * 64);
    const char* Ab = L + cur * 8192;
    const char* Ae = L + 16384 + cur * 8192;
    const char* Bb = L + 32768 + cur * 8192;
    const char* Be = L + 49152 + cur * 8192;
    #pragma unroll
    for (int ks = 0; ks < 2; ++ks) {
      const int slot = ((ks * 4 + fgrp) ^ (frow & 7)) * 16;
      const int brow = (w * 16 + frow) * 128 + slot;
      short8v bbf = *reinterpret_cast<const short8v*>(Bb + brow);
      short8v bef = *reinterpret_cast<const short8v*>(Be + brow);
      #pragma unroll
      for (int m = 0; m < 4; ++m) {
        const int arow = (m * 16 + frow) * 128 + slot;
        short8v abf = *reinterpret_cast<const short8v*>(Ab + arow);
        short8v aef = *reinterpret_cast<const short8v*>(Ae + arow);
        acc[m] = __builtin_amdgcn_mfma_f32_16x16x32_bf16(abf, bbf, acc[m], 0, 0, 0);
        acc[m] = __builtin_amdgcn_mfma_f32_16x16x32_bf16(aef, bbf, acc[m], 0, 0, 0);
        acc[m] = __builtin_amdgcn_mfma_f32_16x16x32_bf16(abf, bef, acc[m], 0, 0, 0);
      }
    }
    asm volatile("s_waitcnt vmcnt(0)");
    __syncthreads();
  }

  float* Pz = Pemb + (long)t * (BB * 2048);
  const int col = n0 + w * 16 + frow;
  #pragma unroll
  for (int m = 0; m < 4; ++m)
    #pragma unroll
    for (int r = 0; r < 4; ++r)
      Pz[(long)(m * 16 + fgrp * 4 + r) * 2048 + col] = acc[m][r];
#undef PE_STAGE
}

// ---------------------------------------------------------------------------
// proj GEMM, split-bf16 MFMA (proven R9).
// ---------------------------------------------------------------------------
__global__ __launch_bounds__(256) void proj_mfma(
    const u16* __restrict__ eb, const u16* __restrict__ ee,   // [3840][1024]
    const u16* __restrict__ wb, const u16* __restrict__ we,   // [512][1024]
    const float* __restrict__ bias,
    float* __restrict__ proj) {                               // [3840][512]
  __shared__ __align__(16) u16 lds[32768];
  const int tid = threadIdx.x;
  const int n0 = blockIdx.x * 64;
  const int m0 = blockIdx.y * 64;
  const int w = tid >> 6, lane = tid & 63;
  const int frow = lane & 15, fgrp = lane >> 4;
  const int srow = tid >> 3, sslot = tid & 7;
  const int scol = (sslot ^ (srow & 7)) * 8;
  char* L = (char*)lds;

#define PJ_STAGE(buf, kc) do {                                                     \
    _Pragma("unroll")                                                              \
    for (int ii = 0; ii < 2; ++ii) {                                               \
      int r_ = ii * 32 + srow;                                                     \
      __builtin_amdgcn_global_load_lds(                                            \
        (const __attribute__((address_space(1))) void*)(eb + (long)(m0 + r_) * ENCD + (kc) + scol), \
        (__attribute__((address_space(3))) void*)(L + (buf) * 8192 + ii * 4096 + tid * 16), 16, 0, 0); \
      __builtin_amdgcn_global_load_lds(                                            \
        (const __attribute__((address_space(1))) void*)(ee + (long)(m0 + r_) * ENCD + (kc) + scol), \
        (__attribute__((address_space(3))) void*)(L + 16384 + (buf) * 8192 + ii * 4096 + tid * 16), 16, 0, 0); \
      __builtin_amdgcn_global_load_lds(                                            \
        (const __attribute__((address_space(1))) void*)(wb + (long)(n0 + r_) * ENCD + (kc) + scol), \
        (__attribute__((address_space(3))) void*)(L + 32768 + (buf) * 8192 + ii * 4096 + tid * 16), 16, 0, 0); \
      __builtin_amdgcn_global_load_lds(                                            \
        (const __attribute__((address_space(1))) void*)(we + (long)(n0 + r_) * ENCD + (kc) + scol), \
        (__attribute__((address_space(3))) void*)(L + 49152 + (buf) * 8192 + ii * 4096 + tid * 16), 16, 0, 0); \
    }                                                                              \
  } while (0)

  f32x4 acc[4] = {{0.f,0.f,0.f,0.f},{0.f,0.f,0.f,0.f},{0.f,0.f,0.f,0.f},{0.f,0.f,0.f,0.f}};

  PJ_STAGE(0, 0);
  asm volatile("s_waitcnt vmcnt(0)");
  __syncthreads();

  for (int kc = 0; kc < 16; ++kc) {
    const int cur = kc & 1;
    if (kc < 15) PJ_STAGE(cur ^ 1, (kc + 1) * 64);
    const char* Ab = L + cur * 8192;
    const char* Ae = L + 16384 + cur * 8192;
    const char* Bb = L + 32768 + cur * 8192;
    const char* Be = L + 49152 + cur * 8192;
    #pragma unroll
    for (int ks = 0; ks < 2; ++ks) {
      const int slot = ((ks * 4 + fgrp) ^ (frow & 7)) * 16;
      const int brow = (w * 16 + frow) * 128 + slot;
      short8v bbf = *reinterpret_cast<const short8v*>(Bb + brow);
      short8v bef = *reinterpret_cast<const short8v*>(Be + brow);
      #pragma unroll
      for (int m = 0; m < 4; ++m) {
        const int arow = (m * 16 + frow) * 128 + slot;
        short8v abf = *reinterpret_cast<const short8v*>(Ab + arow);
        short8v aef = *reinterpret_cast<const short8v*>(Ae + arow);
        acc[m] = __builtin_amdgcn_mfma_f32_16x16x32_bf16(abf, bbf, acc[m], 0, 0, 0);
        acc[m] = __builtin_amdgcn_mfma_f32_16x16x32_bf16(aef, bbf, acc[m], 0, 0, 0);
        acc[m] = __builtin_amdgcn_mfma_f32_16x16x32_bf16(abf, bef, acc[m], 0, 0, 0);
      }
    }
    asm volatile("s_waitcnt vmcnt(0)");
    __syncthreads();
  }

  const int col = n0 + w * 16 + frow;
  const float bv = bias[col];
  #pragma unroll
  for (int m = 0; m < 4; ++m)
    #pragma unroll
    for (int r = 0; r < 4; ++r)
      proj[(long)(m0 + m * 16 + fgrp * 4 + r) * HD + col] = acc[m][r] + bv;
#undef PJ_STAGE
}

// ---------------------------------------------------------------------------
// fc for the last step only (s=18), 512-thr body (R13-verified).
// ---------------------------------------------------------------------------
__global__ __launch_bounds__(512) void fc_last(
    const u16* __restrict__ hb,        // hbuf + 18*B*H
    const u16* __restrict__ Wb,
    const float* __restrict__ bias,
    float* __restrict__ outp) {        // out + 19*VD
  __shared__ __align__(16) u16 lds[40960];   // 80 KB
  const int tid = threadIdx.x;
  const int n0 = blockIdx.x * 256;

  const u16* Ab = hb;
  const u16* Wbase = Wb + (long)n0 * HD;

  const int w = tid >> 6, lane = tid & 63;
  const int frow = lane & 15, fgrp = lane >> 4;
  const int srow = tid >> 3, sslot = tid & 7;   // srow 0..63
  const int scol = (sslot ^ (srow & 7)) * 8;
  char* ldsb = (char*)lds;

#define FL_STAGE(buf, kc) do {                                                    \
    __builtin_amdgcn_global_load_lds(                                             \
        (const __attribute__((address_space(1))) void*)(Ab + srow * HD + (kc) + scol), \
        (__attribute__((address_space(3))) void*)(ldsb + (buf) * 8192 + tid * 16),    \
        16, 0, 0);                                                                \
    _Pragma("unroll")                                                             \
    for (int ii = 0; ii < 4; ++ii) {                                              \
      __builtin_amdgcn_global_load_lds(                                           \
        (const __attribute__((address_space(1))) void*)(Wbase + (long)(ii * 64 + srow) * HD + (kc) + scol), \
        (__attribute__((address_space(3))) void*)(ldsb + 16384 + (buf) * 32768 + ii * 8192 + tid * 16), \
        16, 0, 0);                                                                \
    }                                                                             \
  } while (0)

  f32x4 acc[4][2] = {};

  FL_STAGE(0, 0);
  asm volatile("s_waitcnt vmcnt(0)");
  __syncthreads();

  for (int kc = 0; kc < 8; ++kc) {
    const int cur = kc & 1;
    if (kc < 7) FL_STAGE(cur ^ 1, (kc + 1) * 64);
    const char* Abuf = ldsb + cur * 8192;
    const char* Wbuf = ldsb + 16384 + cur * 32768;
    #pragma unroll
    for (int ks = 0; ks < 2; ++ks) {
      const int slot = ((ks * 4 + fgrp) ^ (frow & 7)) * 16;
      short8v af[4], wf[2];
      #pragma unroll
      for (int m = 0; m < 4; ++m)
        af[m] = *reinterpret_cast<const short8v*>(Abuf + (m * 16 + frow) * 128 + slot);
      #pragma unroll
      for (int n = 0; n < 2; ++n)
        wf[n] = *reinterpret_cast<const short8v*>(Wbuf + (w * 32 + n * 16 + frow) * 128 + slot);
      #pragma unroll
      for (int m = 0; m < 4; ++m)
        #pragma unroll
        for (int n = 0; n < 2; ++n)
          acc[m][n] = __builtin_amdgcn_mfma_f32_16x16x32_bf16(af[m], wf[n], acc[m][n], 0, 0, 0);
    }
    asm volatile("s_waitcnt vmcnt(0)");
    __syncthreads();
  }

  float* Lt = (float*)lds;
  #pragma unroll
  for (int n = 0; n < 2; ++n)
    #pragma unroll
    for (int m = 0; m < 4; ++m)
      #pragma unroll
      for (int r = 0; r < 4; ++r)
        Lt[(m * 16 + fgrp * 4 + r) * 260 + w * 32 + n * 16 + frow] = acc[m][n][r];
  __syncthreads();
  float4 bv4 = *reinterpret_cast<const float4*>(bias + n0 + lane * 4);
  #pragma unroll
  for (int i = 0; i < 8; ++i) {
    int row = i * 8 + w;
    float4 v = *reinterpret_cast<const float4*>(&Lt[row * 260 + lane * 4]);
    v.x += bv4.x; v.y += bv4.y; v.z += bv4.z; v.w += bv4.w;
    *reinterpret_cast<float4*>(outp + (long)row * ((long)TT * VD) + n0 + lane * 4) = v;
  }
#undef FL_STAGE
}

// ---------------------------------------------------------------------------
// v2 fused step kernel (proven R10): grid (64 b, 4 seg), 512 thr.
// ---------------------------------------------------------------------------
__global__ __launch_bounds__(512) void fused_attn_lstm2(
    const float* __restrict__ proj, const float* __restrict__ enc,
    int t,
    const float* __restrict__ P,
    const float* __restrict__ Pemb_prev,
    const float* __restrict__ b_ih, const float* __restrict__ b_hh,
    const float* __restrict__ c_in, float* __restrict__ c_out,
    u16* __restrict__ hbuf_prev,
    float* __restrict__ attn_out,
    u16* __restrict__ xs_bf, u16* __restrict__ xs_er) {
  int b = blockIdx.x, seg = blockIdx.y;
  __shared__ float sh[HD];
  __shared__ float sc[64];
  __shared__ float sw[64];
  int tid = threadIdx.x;
  if (t > 0) {
    int u = tid;
    const float* pe = Pemb_prev + (long)b * 2048;
    float gi = b_ih[u]        + b_hh[u]        + pe[u];
    float gf = b_ih[u + 512]  + b_hh[u + 512]  + pe[u + 512];
    float gg = b_ih[u + 1024] + b_hh[u + 1024] + pe[u + 1024];
    float go = b_ih[u + 1536] + b_hh[u + 1536] + pe[u + 1536];
    #pragma unroll
    for (int ks = 0; ks < 6; ++ks) {
      const float* p = P + ((long)ks * BB + b) * 2048;
      gi += p[u]; gf += p[u + 512]; gg += p[u + 1024]; go += p[u + 1536];
    }
    float si = 1.f / (1.f + __expf(-gi));
    float sf = 1.f / (1.f + __expf(-gf));
    float so = 1.f / (1.f + __expf(-go));
    float tg = tanhf(gg);
    float c2 = sf * c_in[b * HD + u] + si * tg;
    float h2 = so * tanhf(c2);
    sh[u] = h2;
    if (seg == 0) {
      c_out[b * HD + u] = c2;
      u16 hb16 = f2bf(h2);
      hbuf_prev[b * HD + u] = hb16;
      xs_bf[(long)b * 2048 + 1536 + u] = hb16;
      xs_er[(long)b * 2048 + 1536 + u] = f2bf(h2 - bf2f(hb16));
    }
  } else {
    sh[tid] = 0.f;
    if (seg == 0) {
      xs_bf[(long)b * 2048 + 1536 + tid] = 0;
      xs_er[(long)b * 2048 + 1536 + tid] = 0;
    }
  }
  __syncthreads();
  int wave = tid >> 6, lane = tid & 63;
  for (int s = wave; s < SS; s += 8) {
    const float* pr = proj + ((long)b * SS + s) * HD;
    float acc = 0.f;
    #pragma unroll
    for (int k = 0; k < HD / 64; ++k) acc += pr[lane + k * 64] * sh[lane + k * 64];
    #pragma unroll
    for (int off = 32; off; off >>= 1) acc += __shfl_down(acc, off);
    if (lane == 0) sc[s] = acc;
  }
  __syncthreads();
  if (wave == 0) {
    float v = (lane < SS) ? sc[lane] : -INFINITY;
    float m = v;
    #pragma unroll
    for (int off = 32; off; off >>= 1) m = fmaxf(m, __shfl_down(m, off));
    m = __shfl(m, 0);
    float e = (lane < SS) ? __expf(v - m) : 0.f;
    float sum = e;
    #pragma unroll
    for (int off = 32; off; off >>= 1) sum += __shfl_down(sum, off);
    sum = __shfl(sum, 0);
    float wv = e / sum;
    if (lane < SS) {
      sw[lane] = wv;
      if (seg == 0) attn_out[b * SS + lane] = wv;
    }
  }
  __syncthreads();
  if (tid < 256) {
    int e0 = (seg << 8) + tid;
    float acc = 0.f;
    const float* ebp = enc + (long)b * SS * ENCD + e0;
    #pragma unroll
    for (int s = 0; s < SS; ++s) acc += sw[s] * ebp[(long)s * ENCD];
    u16 bb = f2bf(acc);
    xs_bf[(long)b * 2048 + 512 + e0] = bb;
    xs_er[(long)b * 2048 + 512 + e0] = f2bf(acc - bf2f(bb));
  }
}

// ---------------------------------------------------------------------------
// v2 final LSTM (step 18)
// ---------------------------------------------------------------------------
__global__ __launch_bounds__(256) void lstm_final2(
    const float* __restrict__ P, const float* __restrict__ Pemb18,
    const float* __restrict__ b_ih, const float* __restrict__ b_hh,
    const float* __restrict__ c_in, u16* __restrict__ hb) {
  int idx = blockIdx.x * 256 + threadIdx.x;
  int b = idx >> 9, u = idx & 511;
  const float* pe = Pemb18 + (long)b * 2048;
  float gi = b_ih[u]        + b_hh[u]        + pe[u];
  float gf = b_ih[u + 512]  + b_hh[u + 512]  + pe[u + 512];
  float gg = b_ih[u + 1024] + b_hh[u + 1024] + pe[u + 1024];
  float go = b_ih[u + 1536] + b_hh[u + 1536] + pe[u + 1536];
  #pragma unroll
  for (int ks = 0; ks < 6; ++ks) {
    const float* p = P + ((long)ks * BB + b) * 2048;
    gi += p[u]; gf += p[u + 512]; gg += p[u + 1024]; go += p[u + 1536];
  }
  float si = 1.f / (1.f + __expf(-gi));
  float sf = 1.f / (1.f + __expf(-gf));
  float so = 1.f / (1.f + __expf(-go));
  float tg = tanhf(gg);
  float c2 = sf * c_in[idx] + si * tg;
  float h2 = so * tanhf(c2);
  hb[idx] = f2bf(h2);
}

// ---------------------------------------------------------------------------
extern "C" void kernel_launch(void* const* d_in, const int* in_sizes, int n_in,
                              void* d_out_, int out_size, void* d_ws, size_t ws_size,
                              hipStream_t stream) {
  const float* enc   = (const float*)d_in[0];
  const int*   caps  = (const int*)d_in[1];
  const float* emb   = (const float*)d_in[2];
  const float* attnW = (const float*)d_in[3];
  const float* attnB = (const float*)d_in[4];
  const float* W_ih  = (const float*)d_in[5];
  const float* W_hh  = (const float*)d_in[6];
  const float* b_ih  = (const float*)d_in[7];
  const float* b_hh  = (const float*)d_in[8];
  const float* fcW   = (const float*)d_in[9];
  const float* fcb   = (const float*)d_in[10];

  float* out   = (float*)d_out_;                       // [B][T][V]
  float* attns = out + (long)BB * TT * VD;             // [T-1][B][S]

  // workspace layout (floats / u16) — identical to R10/R12/R13
  float* ws    = (float*)d_ws;
  float* proj  = ws;                                   // [3840][512]
  float* h     = proj + (long)BB * SS * HD;
  float* c     = h + BB * HD;                          // cbuf[0]
  float* x     = c + BB * HD;                          // [64][2048] (spare)
  float* P     = x + BB * 2048;                        // [8][64][2048]
  u16*   hbuf  = (u16*)(P + (long)8 * BB * 2048);      // [19][64][512]
  u16*   Wbf   = hbuf + (long)(TT - 1) * BB * HD;      // [V][H]
  u16*   xs_bf = Wbf + (long)VD * HD;                  // [64][2048]
  u16*   xs_er = xs_bf + (long)BB * 2048;              // [64][2048]
  u16*   Wg_bf = xs_er + (long)BB * 2048;              // [2048][2048]
  u16*   Wg_er = Wg_bf + (long)2048 * 2048;            // [2048][2048]
  u16*   enc_bf = Wg_er + (long)2048 * 2048;           // [3840][1024]
  u16*   enc_er = enc_bf + (long)BB * SS * ENCD;       // [3840][1024]
  u16*   aW_bf  = enc_er + (long)BB * SS * ENCD;       // [512][1024]
  u16*   aW_er  = aW_bf + (long)HD * ENCD;             // [512][1024]
  uintptr_t p9 = (uintptr_t)(aW_er + (long)HD * ENCD);
  p9 = (p9 + 15) & ~(uintptr_t)15;
  float* cbuf1   = (float*)p9;                         // [64][512]
  u16*   xemb_bf = (u16*)(cbuf1 + BB * HD);            // [1216][512]
  u16*   xemb_er = xemb_bf + (long)(TT - 1) * BB * ED; // [1216][512]
  uintptr_t pA = (uintptr_t)(xemb_er + (long)(TT - 1) * BB * ED);
  pA = (pA + 15) & ~(uintptr_t)15;
  float* Pemb = (float*)pA;                            // [19][64][2048]
  // ws ≈ 656 MB observed in every pass across rounds 1-13; need ≈ 95 MB.

  init_kernel<<<(BB * VD + 255) / 256, 256, 0, stream>>>(out, h, c);

  {
    long n = (long)VD * HD;
    convert_bf16_k<<<(int)(n / 2048), 256, 0, stream>>>(fcW, Wbf, n);
  }
  split_wg_k<<<2048, 256, 0, stream>>>(W_ih, W_hh, Wg_bf, Wg_er);
  {
    long ne = (long)BB * SS * ENCD;
    split_pair_k<<<(int)(ne / 2048), 256, 0, stream>>>(enc, enc_bf, enc_er, ne);
    long nw = (long)HD * ENCD;
    split_pair_k<<<(int)(nw / 2048), 256, 0, stream>>>(attnW, aW_bf, aW_er, nw);
    proj_mfma<<<dim3(8, 60), 256, 0, stream>>>(enc_bf, enc_er, aW_bf, aW_er,
                                               attnB, proj);
  }
  gather_emb_split<<<(TT - 1) * BB, 256, 0, stream>>>(caps, emb, xemb_bf, xemb_er);
  pemb_mfma<<<dim3(32, TT - 1), 256, 0, stream>>>(xemb_bf, xemb_er, Wg_bf, Wg_er,
                                                  Pemb);

  for (int t = 0; t < TT - 1; ++t) {
    const float* c_in = ((t - 1) & 1) ? cbuf1 : c;
    float* c_out = (t & 1) ? cbuf1 : c;
    u16* hbp = hbuf + (long)(t > 0 ? t - 1 : 0) * BB * HD;
    fused_attn_lstm2<<<dim3(BB, 4), 512, 0, stream>>>(
        proj, enc, t, P,
        Pemb + (long)(t > 0 ? t - 1 : 0) * BB * 2048,
        b_ih, b_hh, c_in, c_out, hbp,
        attns + (long)t * BB * SS, xs_bf, xs_er);
    // gates (z<6) + fc slice for step t-1 (z>=6; hbuf[t-1] just written)
    gates_fc_mfma<<<dim3(32, 1, 10), 256, 0, stream>>>(
        xs_bf + 512, xs_er + 512, Wg_bf + 512, Wg_er + 512, P,
        hbp, Wbf, fcb, out + (long)t * VD, t > 0 ? 1 : 0);
  }
  lstm_final2<<<128, 256, 0, stream>>>(P, Pemb + (long)18 * BB * 2048,
                                       b_ih, b_hh, c,
                                       hbuf + (long)(TT - 2) * BB * HD);

  fc_last<<<125, 512, 0, stream>>>(hbuf + (long)18 * BB * HD, Wbf, fcb,
                                   out + (long)19 * VD);
}

// Round 15
// 451.101 us; speedup vs baseline: 1.1511x; 1.1511x over previous
//
#include <hip/hip_runtime.h>
#include <math.h>
#include <stdint.h>

// Problem dims (fixed by reference)
#define BB   64
#define SS   60
#define ENCD 1024
#define ED   512
#define HD   512
#define VD   32000
#define TT   20

typedef unsigned short u16;
typedef __attribute__((ext_vector_type(8))) short short8v;   // 8 bf16 = 4 VGPR
typedef __attribute__((ext_vector_type(4))) float f32x4;

__device__ __forceinline__ u16 f2bf(float x) {   // RNE float->bf16
  unsigned int u = __float_as_uint(x);
  return (u16)((u + 0x7FFFu + ((u >> 16) & 1u)) >> 16);
}
__device__ __forceinline__ float bf2f(u16 b) {
  return __uint_as_float((unsigned)b << 16);
}

// ---------------------------------------------------------------------------
__global__ __launch_bounds__(256) void init_kernel(float* __restrict__ out,
                                                   float* __restrict__ h,
                                                   float* __restrict__ c) {
  int i = blockIdx.x * 256 + threadIdx.x;
  if (i < BB * VD) {
    int b = i / VD, v = i - b * VD;
    out[(long)b * (TT * VD) + v] = 0.f;
  }
  if (i < BB * HD) { h[i] = 0.f; c[i] = 0.f; }
}

// ---------------------------------------------------------------------------
__global__ __launch_bounds__(256) void convert_bf16_k(const float* __restrict__ src,
                                                      u16* __restrict__ dst, long n) {
  long i = ((long)blockIdx.x * 256 + threadIdx.x) * 8;
  if (i + 8 <= n) {
    float4 a = *reinterpret_cast<const float4*>(src + i);
    float4 b = *reinterpret_cast<const float4*>(src + i + 4);
    uint4 o;
    o.x = (unsigned)f2bf(a.x) | ((unsigned)f2bf(a.y) << 16);
    o.y = (unsigned)f2bf(a.z) | ((unsigned)f2bf(a.w) << 16);
    o.z = (unsigned)f2bf(b.x) | ((unsigned)f2bf(b.y) << 16);
    o.w = (unsigned)f2bf(b.z) | ((unsigned)f2bf(b.w) << 16);
    *reinterpret_cast<uint4*>(dst + i) = o;
  }
}

// ---------------------------------------------------------------------------
__global__ __launch_bounds__(256) void split_pair_k(const float* __restrict__ src,
                                                    u16* __restrict__ bf,
                                                    u16* __restrict__ er, long n) {
  long i = ((long)blockIdx.x * 256 + threadIdx.x) * 8;
  if (i + 8 <= n) {
    #pragma unroll
    for (int j = 0; j < 8; ++j) {
      float v = src[i + j];
      u16 b = f2bf(v);
      bf[i + j] = b;
      er[i + j] = f2bf(v - bf2f(b));
    }
  }
}

// ---------------------------------------------------------------------------
__global__ __launch_bounds__(256) void split_wg_k(
    const float* __restrict__ Wih, const float* __restrict__ Whh,
    u16* __restrict__ wb, u16* __restrict__ we) {
  int n = blockIdx.x;
  int k0 = threadIdx.x * 8;
  #pragma unroll
  for (int j = 0; j < 8; ++j) {
    int k = k0 + j;
    float v = (k < 1536) ? Wih[(long)n * 1536 + k] : Whh[(long)n * 512 + (k - 1536)];
    u16 b = f2bf(v);
    wb[(long)n * 2048 + k] = b;
    we[(long)n * 2048 + k] = f2bf(v - bf2f(b));
  }
}

// ---------------------------------------------------------------------------
__global__ __launch_bounds__(256) void gather_emb_split(
    const int* __restrict__ caps, const float* __restrict__ emb,
    u16* __restrict__ xb, u16* __restrict__ xe) {
  int r = blockIdx.x;                 // 0..1215
  int b = r & 63, t = r >> 6;
  int word = caps[b * TT + t];
  const float* src = emb + (long)word * ED;
  for (int k = threadIdx.x; k < ED; k += 256) {
    float v = src[k];
    u16 bb = f2bf(v);
    xb[(long)r * ED + k] = bb;
    xe[(long)r * ED + k] = f2bf(v - bf2f(bb));
  }
}

// ---------------------------------------------------------------------------
// Gates GEMM, split-bf16 MFMA (proven R8/R10).
// ---------------------------------------------------------------------------
__global__ __launch_bounds__(256) void gates_mfma(
    const u16* __restrict__ xb, const u16* __restrict__ xe,
    const u16* __restrict__ wb, const u16* __restrict__ we,
    float* __restrict__ P) {
  __shared__ __align__(16) u16 lds[32768];   // 64 KB
  const int tid = threadIdx.x;
  const int n0 = blockIdx.x * 64;
  const int kz = blockIdx.z * 256;
  const int w = tid >> 6, lane = tid & 63;
  const int frow = lane & 15, fgrp = lane >> 4;
  const int srow = tid >> 3, sslot = tid & 7;
  const int scol = (sslot ^ (srow & 7)) * 8;
  char* L = (char*)lds;

#define GT_STAGE(buf, kc) do {                                                     \
    _Pragma("unroll")                                                              \
    for (int ii = 0; ii < 2; ++ii) {                                               \
      int r_ = ii * 32 + srow;                                                     \
      __builtin_amdgcn_global_load_lds(                                            \
        (const __attribute__((address_space(1))) void*)(xb + (long)r_ * 2048 + (kc) + scol), \
        (__attribute__((address_space(3))) void*)(L + (buf) * 8192 + ii * 4096 + tid * 16), 16, 0, 0); \
      __builtin_amdgcn_global_load_lds(                                            \
        (const __attribute__((address_space(1))) void*)(xe + (long)r_ * 2048 + (kc) + scol), \
        (__attribute__((address_space(3))) void*)(L + 16384 + (buf) * 8192 + ii * 4096 + tid * 16), 16, 0, 0); \
      __builtin_amdgcn_global_load_lds(                                            \
        (const __attribute__((address_space(1))) void*)(wb + (long)(n0 + r_) * 2048 + (kc) + scol), \
        (__attribute__((address_space(3))) void*)(L + 32768 + (buf) * 8192 + ii * 4096 + tid * 16), 16, 0, 0); \
      __builtin_amdgcn_global_load_lds(                                            \
        (const __attribute__((address_space(1))) void*)(we + (long)(n0 + r_) * 2048 + (kc) + scol), \
        (__attribute__((address_space(3))) void*)(L + 49152 + (buf) * 8192 + ii * 4096 + tid * 16), 16, 0, 0); \
    }                                                                              \
  } while (0)

  f32x4 acc[4] = {{0.f,0.f,0.f,0.f},{0.f,0.f,0.f,0.f},{0.f,0.f,0.f,0.f},{0.f,0.f,0.f,0.f}};

  GT_STAGE(0, kz);
  asm volatile("s_waitcnt vmcnt(0)");
  __syncthreads();

  for (int kc = 0; kc < 4; ++kc) {
    const int cur = kc & 1;
    if (kc < 3) GT_STAGE(cur ^ 1, kz + (kc + 1) * 64);
    const char* Ab = L + cur * 8192;
    const char* Ae = L + 16384 + cur * 8192;
    const char* Bb = L + 32768 + cur * 8192;
    const char* Be = L + 49152 + cur * 8192;
    #pragma unroll
    for (int ks = 0; ks < 2; ++ks) {
      const int slot = ((ks * 4 + fgrp) ^ (frow & 7)) * 16;
      const int brow = (w * 16 + frow) * 128 + slot;
      short8v bbf = *reinterpret_cast<const short8v*>(Bb + brow);
      short8v bef = *reinterpret_cast<const short8v*>(Be + brow);
      #pragma unroll
      for (int m = 0; m < 4; ++m) {
        const int arow = (m * 16 + frow) * 128 + slot;
        short8v abf = *reinterpret_cast<const short8v*>(Ab + arow);
        short8v aef = *reinterpret_cast<const short8v*>(Ae + arow);
        acc[m] = __builtin_amdgcn_mfma_f32_16x16x32_bf16(abf, bbf, acc[m], 0, 0, 0);
        acc[m] = __builtin_amdgcn_mfma_f32_16x16x32_bf16(aef, bbf, acc[m], 0, 0, 0);
        acc[m] = __builtin_amdgcn_mfma_f32_16x16x32_bf16(abf, bef, acc[m], 0, 0, 0);
      }
    }
    asm volatile("s_waitcnt vmcnt(0)");
    __syncthreads();
  }

  float* Pz = P + (long)blockIdx.z * (BB * 2048);
  const int col = n0 + w * 16 + frow;
  #pragma unroll
  for (int m = 0; m < 4; ++m)
    #pragma unroll
    for (int r = 0; r < 4; ++r)
      Pz[(long)(m * 16 + fgrp * 4 + r) * 2048 + col] = acc[m][r];
#undef GT_STAGE
}

// ---------------------------------------------------------------------------
// Pemb batched GEMM (split-bf16 MFMA, proven R10)
// ---------------------------------------------------------------------------
__global__ __launch_bounds__(256) void pemb_mfma(
    const u16* __restrict__ xb, const u16* __restrict__ xe,   // [1216][512]
    const u16* __restrict__ wb, const u16* __restrict__ we,   // [2048][2048] (cols 0..511)
    float* __restrict__ Pemb) {                               // [19][64][2048]
  __shared__ __align__(16) u16 lds[32768];
  const int tid = threadIdx.x;
  const int n0 = blockIdx.x * 64;
  const int t  = blockIdx.y;
  const u16* Ab_g = xb + (long)t * 64 * ED;
  const u16* Ae_g = xe + (long)t * 64 * ED;
  const int w = tid >> 6, lane = tid & 63;
  const int frow = lane & 15, fgrp = lane >> 4;
  const int srow = tid >> 3, sslot = tid & 7;
  const int scol = (sslot ^ (srow & 7)) * 8;
  char* L = (char*)lds;

#define PE_STAGE(buf, kc) do {                                                     \
    _Pragma("unroll")                                                              \
    for (int ii = 0; ii < 2; ++ii) {                                               \
      int r_ = ii * 32 + srow;                                                     \
      __builtin_amdgcn_global_load_lds(                                            \
        (const __attribute__((address_space(1))) void*)(Ab_g + (long)r_ * ED + (kc) + scol), \
        (__attribute__((address_space(3))) void*)(L + (buf) * 8192 + ii * 4096 + tid * 16), 16, 0, 0); \
      __builtin_amdgcn_global_load_lds(                                            \
        (const __attribute__((address_space(1))) void*)(Ae_g + (long)r_ * ED + (kc) + scol), \
        (__attribute__((address_space(3))) void*)(L + 16384 + (buf) * 8192 + ii * 4096 + tid * 16), 16, 0, 0); \
      __builtin_amdgcn_global_load_lds(                                            \
        (const __attribute__((address_space(1))) void*)(wb + (long)(n0 + r_) * 2048 + (kc) + scol), \
        (__attribute__((address_space(3))) void*)(L + 32768 + (buf) * 8192 + ii * 4096 + tid * 16), 16, 0, 0); \
      __builtin_amdgcn_global_load_lds(                                            \
        (const __attribute__((address_space(1))) void*)(we + (long)(n0 + r_) * 2048 + (kc) + scol), \
        (__attribute__((address_space(3))) void*)(L + 49152 + (buf) * 8192 + ii * 4096 + tid * 16), 16, 0, 0); \
    }                                                                              \
  } while (0)

  f32x4 acc[4] = {{0.f,0.f,0.f,0.f},{0.f,0.f,0.f,0.f},{0.f,0.f,0.f,0.f},{0.f,0.f,0.f,0.f}};

  PE_STAGE(0, 0);
  asm volatile("s_waitcnt vmcnt(0)");
  __syncthreads();

  for (int kc = 0; kc < 8; ++kc) {
    const int cur = kc & 1;
    if (kc < 7) PE_STAGE(cur ^ 1, (kc + 1) * 64);
    const char* Ab = L + cur * 8192;
    const char* Ae = L + 16384 + cur * 8192;
    const char* Bb = L + 32768 + cur * 8192;
    const char* Be = L + 49152 + cur * 8192;
    #pragma unroll
    for (int ks = 0; ks < 2; ++ks) {
      const int slot = ((ks * 4 + fgrp) ^ (frow & 7)) * 16;
      const int brow = (w * 16 + frow) * 128 + slot;
      short8v bbf = *reinterpret_cast<const short8v*>(Bb + brow);
      short8v bef = *reinterpret_cast<const short8v*>(Be + brow);
      #pragma unroll
      for (int m = 0; m < 4; ++m) {
        const int arow = (m * 16 + frow) * 128 + slot;
        short8v abf = *reinterpret_cast<const short8v*>(Ab + arow);
        short8v aef = *reinterpret_cast<const short8v*>(Ae + arow);
        acc[m] = __builtin_amdgcn_mfma_f32_16x16x32_bf16(abf, bbf, acc[m], 0, 0, 0);
        acc[m] = __builtin_amdgcn_mfma_f32_16x16x32_bf16(aef, bbf, acc[m], 0, 0, 0);
        acc[m] = __builtin_amdgcn_mfma_f32_16x16x32_bf16(abf, bef, acc[m], 0, 0, 0);
      }
    }
    asm volatile("s_waitcnt vmcnt(0)");
    __syncthreads();
  }

  float* Pz = Pemb + (long)t * (BB * 2048);
  const int col = n0 + w * 16 + frow;
  #pragma unroll
  for (int m = 0; m < 4; ++m)
    #pragma unroll
    for (int r = 0; r < 4; ++r)
      Pz[(long)(m * 16 + fgrp * 4 + r) * 2048 + col] = acc[m][r];
#undef PE_STAGE
}

// ---------------------------------------------------------------------------
// proj GEMM, split-bf16 MFMA (proven R9).
// ---------------------------------------------------------------------------
__global__ __launch_bounds__(256) void proj_mfma(
    const u16* __restrict__ eb, const u16* __restrict__ ee,   // [3840][1024]
    const u16* __restrict__ wb, const u16* __restrict__ we,   // [512][1024]
    const float* __restrict__ bias,
    float* __restrict__ proj) {                               // [3840][512]
  __shared__ __align__(16) u16 lds[32768];
  const int tid = threadIdx.x;
  const int n0 = blockIdx.x * 64;
  const int m0 = blockIdx.y * 64;
  const int w = tid >> 6, lane = tid & 63;
  const int frow = lane & 15, fgrp = lane >> 4;
  const int srow = tid >> 3, sslot = tid & 7;
  const int scol = (sslot ^ (srow & 7)) * 8;
  char* L = (char*)lds;

#define PJ_STAGE(buf, kc) do {                                                     \
    _Pragma("unroll")                                                              \
    for (int ii = 0; ii < 2; ++ii) {                                               \
      int r_ = ii * 32 + srow;                                                     \
      __builtin_amdgcn_global_load_lds(                                            \
        (const __attribute__((address_space(1))) void*)(eb + (long)(m0 + r_) * ENCD + (kc) + scol), \
        (__attribute__((address_space(3))) void*)(L + (buf) * 8192 + ii * 4096 + tid * 16), 16, 0, 0); \
      __builtin_amdgcn_global_load_lds(                                            \
        (const __attribute__((address_space(1))) void*)(ee + (long)(m0 + r_) * ENCD + (kc) + scol), \
        (__attribute__((address_space(3))) void*)(L + 16384 + (buf) * 8192 + ii * 4096 + tid * 16), 16, 0, 0); \
      __builtin_amdgcn_global_load_lds(                                            \
        (const __attribute__((address_space(1))) void*)(wb + (long)(n0 + r_) * ENCD + (kc) + scol), \
        (__attribute__((address_space(3))) void*)(L + 32768 + (buf) * 8192 + ii * 4096 + tid * 16), 16, 0, 0); \
      __builtin_amdgcn_global_load_lds(                                            \
        (const __attribute__((address_space(1))) void*)(we + (long)(n0 + r_) * ENCD + (kc) + scol), \
        (__attribute__((address_space(3))) void*)(L + 49152 + (buf) * 8192 + ii * 4096 + tid * 16), 16, 0, 0); \
    }                                                                              \
  } while (0)

  f32x4 acc[4] = {{0.f,0.f,0.f,0.f},{0.f,0.f,0.f,0.f},{0.f,0.f,0.f,0.f},{0.f,0.f,0.f,0.f}};

  PJ_STAGE(0, 0);
  asm volatile("s_waitcnt vmcnt(0)");
  __syncthreads();

  for (int kc = 0; kc < 16; ++kc) {
    const int cur = kc & 1;
    if (kc < 15) PJ_STAGE(cur ^ 1, (kc + 1) * 64);
    const char* Ab = L + cur * 8192;
    const char* Ae = L + 16384 + cur * 8192;
    const char* Bb = L + 32768 + cur * 8192;
    const char* Be = L + 49152 + cur * 8192;
    #pragma unroll
    for (int ks = 0; ks < 2; ++ks) {
      const int slot = ((ks * 4 + fgrp) ^ (frow & 7)) * 16;
      const int brow = (w * 16 + frow) * 128 + slot;
      short8v bbf = *reinterpret_cast<const short8v*>(Bb + brow);
      short8v bef = *reinterpret_cast<const short8v*>(Be + brow);
      #pragma unroll
      for (int m = 0; m < 4; ++m) {
        const int arow = (m * 16 + frow) * 128 + slot;
        short8v abf = *reinterpret_cast<const short8v*>(Ab + arow);
        short8v aef = *reinterpret_cast<const short8v*>(Ae + arow);
        acc[m] = __builtin_amdgcn_mfma_f32_16x16x32_bf16(abf, bbf, acc[m], 0, 0, 0);
        acc[m] = __builtin_amdgcn_mfma_f32_16x16x32_bf16(aef, bbf, acc[m], 0, 0, 0);
        acc[m] = __builtin_amdgcn_mfma_f32_16x16x32_bf16(abf, bef, acc[m], 0, 0, 0);
      }
    }
    asm volatile("s_waitcnt vmcnt(0)");
    __syncthreads();
  }

  const int col = n0 + w * 16 + frow;
  const float bv = bias[col];
  #pragma unroll
  for (int m = 0; m < 4; ++m)
    #pragma unroll
    for (int r = 0; r < 4; ++r)
      proj[(long)(m0 + m * 16 + fgrp * 4 + r) * HD + col] = acc[m][r] + bv;
#undef PJ_STAGE
}

// ---------------------------------------------------------------------------
// fc GEMM v3 (R13-verified): 512 threads / 8 waves, 64Mx256N tile, BK=64x8,
// double-buffered global_load_lds + XOR swizzle, coalesced LDS epilogue.
// ---------------------------------------------------------------------------
__global__ __launch_bounds__(512) void fc_tiled(
    const u16* __restrict__ hbuf, const u16* __restrict__ Wb,
    const float* __restrict__ bias, float* __restrict__ out) {
  __shared__ __align__(16) u16 lds[40960];   // 80 KB
  const int tid = threadIdx.x;
  const int bid = blockIdx.x;
  const int xcd = bid & 7, loc = bid >> 3;
  const int wg = (xcd < 7) ? (xcd * 297 + loc) : (2079 + loc);
  const int n_tile = wg / 19, t = wg - n_tile * 19;
  const int n0 = n_tile * 256;

  const u16* Ab = hbuf + (long)t * (BB * HD);
  const u16* Wbase = Wb + (long)n0 * HD;

  const int w = tid >> 6, lane = tid & 63;
  const int frow = lane & 15, fgrp = lane >> 4;
  const int srow = tid >> 3, sslot = tid & 7;   // srow 0..63 (512 thr)
  const int scol = (sslot ^ (srow & 7)) * 8;
  char* ldsb = (char*)lds;

#define FC_STAGE(buf, kc) do {                                                    \
    __builtin_amdgcn_global_load_lds(                                             \
        (const __attribute__((address_space(1))) void*)(Ab + srow * HD + (kc) + scol), \
        (__attribute__((address_space(3))) void*)(ldsb + (buf) * 8192 + tid * 16),    \
        16, 0, 0);                                                                \
    _Pragma("unroll")                                                             \
    for (int ii = 0; ii < 4; ++ii) {                                              \
      __builtin_amdgcn_global_load_lds(                                           \
        (const __attribute__((address_space(1))) void*)(Wbase + (long)(ii * 64 + srow) * HD + (kc) + scol), \
        (__attribute__((address_space(3))) void*)(ldsb + 16384 + (buf) * 32768 + ii * 8192 + tid * 16), \
        16, 0, 0);                                                                \
    }                                                                             \
  } while (0)

  f32x4 acc[4][2] = {};

  FC_STAGE(0, 0);
  asm volatile("s_waitcnt vmcnt(0)");
  __syncthreads();

  for (int kc = 0; kc < 8; ++kc) {
    const int cur = kc & 1;
    if (kc < 7) FC_STAGE(cur ^ 1, (kc + 1) * 64);
    const char* Abuf = ldsb + cur * 8192;
    const char* Wbuf = ldsb + 16384 + cur * 32768;
    #pragma unroll
    for (int ks = 0; ks < 2; ++ks) {
      const int slot = ((ks * 4 + fgrp) ^ (frow & 7)) * 16;
      short8v af[4], wf[2];
      #pragma unroll
      for (int m = 0; m < 4; ++m)
        af[m] = *reinterpret_cast<const short8v*>(Abuf + (m * 16 + frow) * 128 + slot);
      #pragma unroll
      for (int n = 0; n < 2; ++n)
        wf[n] = *reinterpret_cast<const short8v*>(Wbuf + (w * 32 + n * 16 + frow) * 128 + slot);
      #pragma unroll
      for (int m = 0; m < 4; ++m)
        #pragma unroll
        for (int n = 0; n < 2; ++n)
          acc[m][n] = __builtin_amdgcn_mfma_f32_16x16x32_bf16(af[m], wf[n], acc[m][n], 0, 0, 0);
    }
    asm volatile("s_waitcnt vmcnt(0)");
    __syncthreads();
  }

  // epilogue: stage 64x256 tile into LDS (stride 260), coalesced stores
  float* Lt = (float*)lds;     // 64*260*4 = 66560 B <= 80 KB
  #pragma unroll
  for (int n = 0; n < 2; ++n)
    #pragma unroll
    for (int m = 0; m < 4; ++m)
      #pragma unroll
      for (int r = 0; r < 4; ++r)
        Lt[(m * 16 + fgrp * 4 + r) * 260 + w * 32 + n * 16 + frow] = acc[m][n][r];
  __syncthreads();
  float4 bv4 = *reinterpret_cast<const float4*>(bias + n0 + lane * 4);
  #pragma unroll
  for (int i = 0; i < 8; ++i) {
    int row = i * 8 + w;       // batch index b (0..63)
    float4 v = *reinterpret_cast<const float4*>(&Lt[row * 260 + lane * 4]);
    v.x += bv4.x; v.y += bv4.y; v.z += bv4.z; v.w += bv4.w;
    *reinterpret_cast<float4*>(out + ((long)row * TT + (t + 1)) * VD + n0 + lane * 4) = v;
  }
#undef FC_STAGE
}

// ---------------------------------------------------------------------------
// v2 fused step kernel (proven R10): grid (64 b, 4 seg), 512 thr.
// ---------------------------------------------------------------------------
__global__ __launch_bounds__(512) void fused_attn_lstm2(
    const float* __restrict__ proj, const float* __restrict__ enc,
    int t,
    const float* __restrict__ P,
    const float* __restrict__ Pemb_prev,
    const float* __restrict__ b_ih, const float* __restrict__ b_hh,
    const float* __restrict__ c_in, float* __restrict__ c_out,
    u16* __restrict__ hbuf_prev,
    float* __restrict__ attn_out,
    u16* __restrict__ xs_bf, u16* __restrict__ xs_er) {
  int b = blockIdx.x, seg = blockIdx.y;
  __shared__ float sh[HD];
  __shared__ float sc[64];
  __shared__ float sw[64];
  int tid = threadIdx.x;
  if (t > 0) {
    int u = tid;
    const float* pe = Pemb_prev + (long)b * 2048;
    float gi = b_ih[u]        + b_hh[u]        + pe[u];
    float gf = b_ih[u + 512]  + b_hh[u + 512]  + pe[u + 512];
    float gg = b_ih[u + 1024] + b_hh[u + 1024] + pe[u + 1024];
    float go = b_ih[u + 1536] + b_hh[u + 1536] + pe[u + 1536];
    #pragma unroll
    for (int ks = 0; ks < 6; ++ks) {
      const float* p = P + ((long)ks * BB + b) * 2048;
      gi += p[u]; gf += p[u + 512]; gg += p[u + 1024]; go += p[u + 1536];
    }
    float si = 1.f / (1.f + __expf(-gi));
    float sf = 1.f / (1.f + __expf(-gf));
    float so = 1.f / (1.f + __expf(-go));
    float tg = tanhf(gg);
    float c2 = sf * c_in[b * HD + u] + si * tg;
    float h2 = so * tanhf(c2);
    sh[u] = h2;
    if (seg == 0) {
      c_out[b * HD + u] = c2;
      u16 hb16 = f2bf(h2);
      hbuf_prev[b * HD + u] = hb16;
      xs_bf[(long)b * 2048 + 1536 + u] = hb16;
      xs_er[(long)b * 2048 + 1536 + u] = f2bf(h2 - bf2f(hb16));
    }
  } else {
    sh[tid] = 0.f;
    if (seg == 0) {
      xs_bf[(long)b * 2048 + 1536 + tid] = 0;
      xs_er[(long)b * 2048 + 1536 + tid] = 0;
    }
  }
  __syncthreads();
  int wave = tid >> 6, lane = tid & 63;
  for (int s = wave; s < SS; s += 8) {
    const float* pr = proj + ((long)b * SS + s) * HD;
    float acc = 0.f;
    #pragma unroll
    for (int k = 0; k < HD / 64; ++k) acc += pr[lane + k * 64] * sh[lane + k * 64];
    #pragma unroll
    for (int off = 32; off; off >>= 1) acc += __shfl_down(acc, off);
    if (lane == 0) sc[s] = acc;
  }
  __syncthreads();
  if (wave == 0) {
    float v = (lane < SS) ? sc[lane] : -INFINITY;
    float m = v;
    #pragma unroll
    for (int off = 32; off; off >>= 1) m = fmaxf(m, __shfl_down(m, off));
    m = __shfl(m, 0);
    float e = (lane < SS) ? __expf(v - m) : 0.f;
    float sum = e;
    #pragma unroll
    for (int off = 32; off; off >>= 1) sum += __shfl_down(sum, off);
    sum = __shfl(sum, 0);
    float wv = e / sum;
    if (lane < SS) {
      sw[lane] = wv;
      if (seg == 0) attn_out[b * SS + lane] = wv;
    }
  }
  __syncthreads();
  if (tid < 256) {
    int e0 = (seg << 8) + tid;
    float acc = 0.f;
    const float* ebp = enc + (long)b * SS * ENCD + e0;
    #pragma unroll
    for (int s = 0; s < SS; ++s) acc += sw[s] * ebp[(long)s * ENCD];
    u16 bb = f2bf(acc);
    xs_bf[(long)b * 2048 + 512 + e0] = bb;
    xs_er[(long)b * 2048 + 512 + e0] = f2bf(acc - bf2f(bb));
  }
}

// ---------------------------------------------------------------------------
// v2 final LSTM (step 18)
// ---------------------------------------------------------------------------
__global__ __launch_bounds__(256) void lstm_final2(
    const float* __restrict__ P, const float* __restrict__ Pemb18,
    const float* __restrict__ b_ih, const float* __restrict__ b_hh,
    const float* __restrict__ c_in, u16* __restrict__ hb) {
  int idx = blockIdx.x * 256 + threadIdx.x;
  int b = idx >> 9, u = idx & 511;
  const float* pe = Pemb18 + (long)b * 2048;
  float gi = b_ih[u]        + b_hh[u]        + pe[u];
  float gf = b_ih[u + 512]  + b_hh[u + 512]  + pe[u + 512];
  float gg = b_ih[u + 1024] + b_hh[u + 1024] + pe[u + 1024];
  float go = b_ih[u + 1536] + b_hh[u + 1536] + pe[u + 1536];
  #pragma unroll
  for (int ks = 0; ks < 6; ++ks) {
    const float* p = P + ((long)ks * BB + b) * 2048;
    gi += p[u]; gf += p[u + 512]; gg += p[u + 1024]; go += p[u + 1536];
  }
  float si = 1.f / (1.f + __expf(-gi));
  float sf = 1.f / (1.f + __expf(-gf));
  float so = 1.f / (1.f + __expf(-go));
  float tg = tanhf(gg);
  float c2 = sf * c_in[idx] + si * tg;
  float h2 = so * tanhf(c2);
  hb[idx] = f2bf(h2);
}

// ---------------------------------------------------------------------------
extern "C" void kernel_launch(void* const* d_in, const int* in_sizes, int n_in,
                              void* d_out_, int out_size, void* d_ws, size_t ws_size,
                              hipStream_t stream) {
  const float* enc   = (const float*)d_in[0];
  const int*   caps  = (const int*)d_in[1];
  const float* emb   = (const float*)d_in[2];
  const float* attnW = (const float*)d_in[3];
  const float* attnB = (const float*)d_in[4];
  const float* W_ih  = (const float*)d_in[5];
  const float* W_hh  = (const float*)d_in[6];
  const float* b_ih  = (const float*)d_in[7];
  const float* b_hh  = (const float*)d_in[8];
  const float* fcW   = (const float*)d_in[9];
  const float* fcb   = (const float*)d_in[10];

  float* out   = (float*)d_out_;                       // [B][T][V]
  float* attns = out + (long)BB * TT * VD;             // [T-1][B][S]

  // workspace layout (floats / u16) — identical to R10/R12/R13
  float* ws    = (float*)d_ws;
  float* proj  = ws;                                   // [3840][512]
  float* h     = proj + (long)BB * SS * HD;
  float* c     = h + BB * HD;                          // cbuf[0]
  float* x     = c + BB * HD;                          // [64][2048] (spare)
  float* P     = x + BB * 2048;                        // [8][64][2048]
  u16*   hbuf  = (u16*)(P + (long)8 * BB * 2048);      // [19][64][512]
  u16*   Wbf   = hbuf + (long)(TT - 1) * BB * HD;      // [V][H]
  u16*   xs_bf = Wbf + (long)VD * HD;                  // [64][2048]
  u16*   xs_er = xs_bf + (long)BB * 2048;              // [64][2048]
  u16*   Wg_bf = xs_er + (long)BB * 2048;              // [2048][2048]
  u16*   Wg_er = Wg_bf + (long)2048 * 2048;            // [2048][2048]
  u16*   enc_bf = Wg_er + (long)2048 * 2048;           // [3840][1024]
  u16*   enc_er = enc_bf + (long)BB * SS * ENCD;       // [3840][1024]
  u16*   aW_bf  = enc_er + (long)BB * SS * ENCD;       // [512][1024]
  u16*   aW_er  = aW_bf + (long)HD * ENCD;             // [512][1024]
  uintptr_t p9 = (uintptr_t)(aW_er + (long)HD * ENCD);
  p9 = (p9 + 15) & ~(uintptr_t)15;
  float* cbuf1   = (float*)p9;                         // [64][512]
  u16*   xemb_bf = (u16*)(cbuf1 + BB * HD);            // [1216][512]
  u16*   xemb_er = xemb_bf + (long)(TT - 1) * BB * ED; // [1216][512]
  uintptr_t pA = (uintptr_t)(xemb_er + (long)(TT - 1) * BB * ED);
  pA = (pA + 15) & ~(uintptr_t)15;
  float* Pemb = (float*)pA;                            // [19][64][2048]
  // ws ≈ 656 MB observed in every pass across rounds 1-14; need ≈ 95 MB.

  init_kernel<<<(BB * VD + 255) / 256, 256, 0, stream>>>(out, h, c);

  {
    long n = (long)VD * HD;
    convert_bf16_k<<<(int)(n / 2048), 256, 0, stream>>>(fcW, Wbf, n);
  }
  split_wg_k<<<2048, 256, 0, stream>>>(W_ih, W_hh, Wg_bf, Wg_er);
  {
    long ne = (long)BB * SS * ENCD;
    split_pair_k<<<(int)(ne / 2048), 256, 0, stream>>>(enc, enc_bf, enc_er, ne);
    long nw = (long)HD * ENCD;
    split_pair_k<<<(int)(nw / 2048), 256, 0, stream>>>(attnW, aW_bf, aW_er, nw);
    proj_mfma<<<dim3(8, 60), 256, 0, stream>>>(enc_bf, enc_er, aW_bf, aW_er,
                                               attnB, proj);
  }
  gather_emb_split<<<(TT - 1) * BB, 256, 0, stream>>>(caps, emb, xemb_bf, xemb_er);
  pemb_mfma<<<dim3(32, TT - 1), 256, 0, stream>>>(xemb_bf, xemb_er, Wg_bf, Wg_er,
                                                  Pemb);

  for (int t = 0; t < TT - 1; ++t) {
    const float* c_in = ((t - 1) & 1) ? cbuf1 : c;
    float* c_out = (t & 1) ? cbuf1 : c;
    u16* hbp = hbuf + (long)(t > 0 ? t - 1 : 0) * BB * HD;
    fused_attn_lstm2<<<dim3(BB, 4), 512, 0, stream>>>(
        proj, enc, t, P,
        Pemb + (long)(t > 0 ? t - 1 : 0) * BB * 2048,
        b_ih, b_hh, c_in, c_out, hbp,
        attns + (long)t * BB * SS, xs_bf, xs_er);
    gates_mfma<<<dim3(32, 1, 6), 256, 0, stream>>>(
        xs_bf + 512, xs_er + 512, Wg_bf + 512, Wg_er + 512, P);
  }
  lstm_final2<<<128, 256, 0, stream>>>(P, Pemb + (long)18 * BB * 2048,
                                       b_ih, b_hh, c,
                                       hbuf + (long)(TT - 2) * BB * HD);

  fc_tiled<<<125 * 19, 512, 0, stream>>>(hbuf, Wbf, fcb, out);
}